// Round 12
// baseline (333.814 us; speedup 1.0000x reference)
//
#include <hip/hip_runtime.h>
#include <stdint.h>

typedef short s16x8 __attribute__((ext_vector_type(8)));
typedef float f32x4 __attribute__((ext_vector_type(4)));
typedef uint32_t u32x4 __attribute__((ext_vector_type(4)));

#define MFMA16(a, b, c) __builtin_amdgcn_mfma_f32_16x16x32_bf16(a, b, c, 0, 0, 0)
#define GEMM_BLK 1024

__device__ __forceinline__ short f2bf(float f) {
  uint32_t u = __builtin_bit_cast(uint32_t, f);
  u += 0x7FFFu + ((u >> 16) & 1u);   // round-to-nearest-even
  return (short)(u >> 16);
}
// 1-op f32->bf16 via HW packed convert (RNE); low 16 bits = cvt(lo).
__device__ __forceinline__ uint32_t cvtpk(float lo, float hi) {
  uint32_t r;
  asm("v_cvt_pk_bf16_f32 %0, %1, %2" : "=v"(r) : "v"(lo), "v"(hi));
  return r;
}
__device__ __forceinline__ short f2bf1(float f) { return (short)cvtpk(f, f); }

// Raw barrier WITHOUT vmcnt drain: wave commits its LDS ops (lgkmcnt) then
// barriers.  In-flight global loads survive; the compiler inserts waits
// before their USE (m201/HK pattern).  Memory clobbers pin compile-time
// ordering of LDS ops around the barrier.
__device__ __forceinline__ void bsync() {
  asm volatile("s_waitcnt lgkmcnt(0)" ::: "memory");
  __builtin_amdgcn_s_barrier();
  asm volatile("" ::: "memory");
}

// ---------------------------------------------------------------------------
// Weight pre-pack (unchanged from R11): bf16 MFMA fragment order
// (idx16 = lane&15, k = ks*32 + (lane>>4)*8 + e).  W0 0..15, GB 16..111,
// WH 112..175, D1 176..191 (192 KiB) + decoder bias pack dpk (8 KiB f32).
// ---------------------------------------------------------------------------
__global__ void pack_w(const float* __restrict__ w0, const float* __restrict__ wh,
                       const float* __restrict__ gw, const float* __restrict__ bw,
                       const float* __restrict__ d1, const float* __restrict__ d1bp,
                       const float* __restrict__ d2wp, short* __restrict__ out,
                       float* __restrict__ dpk) {
  int idx = blockIdx.x * 512 + threadIdx.x;
  if (idx < 98304) {
    int f = idx >> 9;
    int r = idx & 511;
    int lane = r >> 3, e = r & 7;
    int kk = ((lane >> 4) << 3) + e;
    int nn = lane & 15;
    float v;
    if (f < 16) {
      int ct = f >> 1, ks = f & 1;
      int k = ks * 32 + kk, n = ct * 16 + nn;
      if (k < 48) v = w0[(1 + k) * 128 + n];
      else if (k == 48) v = w0[n];
      else v = 0.f;
    } else if (f < 112) {
      int f2 = f - 16;
      int ks = f2 & 1, ct = (f2 >> 1) & 7, gb = (f2 >> 4) & 1, l = f2 >> 5;
      int k = ks * 32 + kk, n = ct * 16 + nn;
      const float* Wp = gb ? bw : gw;
      v = Wp[(l * 64 + k) * 128 + n];
    } else if (f < 176) {
      int f2 = f - 112;
      int ks = f2 & 3, ct = (f2 >> 2) & 7, i = f2 >> 5;
      int k = ks * 32 + kk, n = ct * 16 + nn;
      v = wh[(i * 128 + k) * 128 + n];
    } else {
      int f2 = f - 176;
      int ks = f2 & 3, ct = f2 >> 2;
      int k = ks * 32 + kk, n = ct * 16 + nn;
      v = d1[k * 64 + n];
    }
    out[idx] = f2bf(v);
  } else if (idx < 100352) {
    int j = idx - 98304;             // 0..2047
    int which = j >> 10;
    int k = j & 1023;
    int ct = k >> 8, lane = (k >> 2) & 63, rr = k & 3;
    int n2 = ct * 16 + ((lane >> 4) << 2) + rr;
    dpk[j] = which ? d2wp[n2] : d1bp[n2];
  }
}

// ---------------------------------------------------------------------------
// Producer (unchanged from R10): bilinear gathers -> feat tiles in d_ws in
// MFMA A-frag layout (8 frags x 1KB per 64-row tile).  No LDS, no barriers.
// ---------------------------------------------------------------------------
__global__ __launch_bounds__(512) void ngc_gather(
    const float* __restrict__ coords, const float* __restrict__ angles,
    const float* __restrict__ rho, const float* __restrict__ rho_n,
    const float* __restrict__ gt0, const float* __restrict__ gr0,
    const float* __restrict__ gt1, const float* __restrict__ gr1,
    const float* __restrict__ gt2, const float* __restrict__ gr2,
    short* __restrict__ stage, int n, int t0) {
  const int tid = threadIdx.x;
  const int row0 = (t0 + blockIdx.x) * 64;
  char* st = (char*)(stage + (size_t)blockIdx.x * 4096);

  if (tid < 384) {
    int r = tid & 63, g = tid >> 6;
    int gr_ = row0 + r; gr_ = gr_ < n ? gr_ : n - 1;
    float vv = coords[gr_];
    float u = (g < 3) ? angles[gr_] : rho_n[gr_];
    int lvl = (g < 3) ? g : g - 3;
    const float* G = (g == 0) ? gt0 : (g == 1) ? gt1 : (g == 2) ? gt2
                   : (g == 3) ? gr0 : (g == 4) ? gr1 : gr2;
    int Wg = 128 << lvl;
    float x = u * (float)(Wg - 1), y = vv * (float)(Wg - 1);
    int ix = (int)x; ix = ix < 0 ? 0 : (ix > Wg - 2 ? Wg - 2 : ix);
    int iy = (int)y; iy = iy < 0 ? 0 : (iy > Wg - 2 ? Wg - 2 : iy);
    float wx = x - (float)ix, wy = y - (float)iy;
    const float4* p0 = (const float4*)(G + (size_t)(iy * Wg + ix) * 8);
    const float4* p1 = (const float4*)(G + (size_t)((iy + 1) * Wg + ix) * 8);
    float4 c00a = p0[0], c00b = p0[1], c01a = p0[2], c01b = p0[3];
    float4 c10a = p1[0], c10b = p1[1], c11a = p1[2], c11b = p1[3];
    float w00 = (1.f - wx) * (1.f - wy), w01 = wx * (1.f - wy);
    float w10 = (1.f - wx) * wy, w11 = wx * wy;
    float e0 = c00a.x * w00 + c01a.x * w01 + c10a.x * w10 + c11a.x * w11;
    float e1 = c00a.y * w00 + c01a.y * w01 + c10a.y * w10 + c11a.y * w11;
    float e2 = c00a.z * w00 + c01a.z * w01 + c10a.z * w10 + c11a.z * w11;
    float e3 = c00a.w * w00 + c01a.w * w01 + c10a.w * w10 + c11a.w * w11;
    float e4 = c00b.x * w00 + c01b.x * w01 + c10b.x * w10 + c11b.x * w11;
    float e5 = c00b.y * w00 + c01b.y * w01 + c10b.y * w10 + c11b.y * w11;
    float e6 = c00b.z * w00 + c01b.z * w01 + c10b.z * w10 + c11b.z * w11;
    float e7 = c00b.w * w00 + c01b.w * w01 + c10b.w * w10 + c11b.w * w11;
    u32x4 o = { cvtpk(e0, e1), cvtpk(e2, e3), cvtpk(e4, e5), cvtpk(e6, e7) };
    int dst16 = ((r >> 4) * 2 + (g >> 2)) * 64 + (g & 3) * 16 + (r & 15);
    *(u32x4*)(st + dst16 * 16) = o;
  } else if (tid < 448) {
    int r = tid - 384;
    int gr_ = row0 + r; gr_ = gr_ < n ? gr_ : n - 1;
    s16x8 a = { f2bf1(rho[gr_]), 0, 0, 0, 0, 0, 0, 0 };
    int base = ((r >> 4) * 2 + 1) * 64;
    *(s16x8*)(st + (base + 32 + (r & 15)) * 16) = a;
  } else {
    int r = tid - 448;
    s16x8 z = { 0, 0, 0, 0, 0, 0, 0, 0 };
    int base = ((r >> 4) * 2 + 1) * 64;
    *(s16x8*)(st + (base + 48 + (r & 15)) * 16) = z;
  }
}

// ---------------------------------------------------------------------------
// R12 consumer: persistent blocks + raw-barrier pipeline.
// Per tile: stage(cf) | b1 | L0->x0 | b2 | R1 x0->x1 | b3 | R2 x1->x0 | b4 |
// decoder(waves 0-3) -> out.  All barriers are lgkmcnt(0)+s_barrier (NO
// vmcnt drain).  cf prefetch for tile t+stride issued right after the stage
// convert consumes it; ts prefetch right after L0's epilogue consumes tsr —
// both stay in flight across the barriers and are waited only at use.
// LDS 40KB = cfA 8K + x0 16K + x1 16K.
// ---------------------------------------------------------------------------
__global__ __launch_bounds__(512) void ngc_gemm(
    const float* __restrict__ cf, const float* __restrict__ ts,
    const float* __restrict__ f0b, const float* __restrict__ fhb,
    const float* __restrict__ gab, const float* __restrict__ beb,
    const float* __restrict__ d2b, const short* __restrict__ pw,
    const float* __restrict__ dpk, const short* __restrict__ stage,
    float* __restrict__ out, int n, int t0, int ntc) {
  __shared__ __align__(16) char smem[40 * 1024];
  char* cfA = smem;                 // 8 KiB: frag = rg*2+ks (ks<2)
  char* x0  = smem + 8 * 1024;      // 16 KiB: frag = rg*4+ks (ks<4)
  char* x1  = smem + 24 * 1024;     // 16 KiB

  const int tid = threadIdx.x;
  const int lane = tid & 63;
  const int w = tid >> 6;           // wave id == col-tile ct, 0..7
  const int g16 = lane >> 4;
  const int l15 = lane & 15;
  const int col = w * 16 + l15;
  const int cbase = col >> 5;
  const int cslot = ((col >> 3) & 3) * 16;
  const int ce = (col & 7) * 2;
  const int cb = tid & 7, rcf = tid >> 3;

  const float d2b0 = d2b[0];

  // loop-carried prefetch registers
  float4 cfr0, cfr1;
  float tsr[4][4];

  auto issueA = [&](int tt2) {      // cf for tile tt2
    int gr_ = (t0 + tt2) * 64 + rcf; gr_ = gr_ < n ? gr_ : n - 1;
    const float4* cp = (const float4*)(cf + (size_t)gr_ * 64 + cb * 8);
    cfr0 = cp[0]; cfr1 = cp[1];
  };
  auto issueT = [&](int tt2) {      // ts for tile tt2
    int row0n = (t0 + tt2) * 64;
#pragma unroll
    for (int rg = 0; rg < 4; ++rg)
#pragma unroll
      for (int rr = 0; rr < 4; ++rr) {
        int grow = row0n + rg * 16 + g16 * 4 + rr; grow = grow < n ? grow : n - 1;
        tsr[rg][rr] = ts[(size_t)grow * 128 + col];
      }
  };

  auto ldF = [&](const char* b, int frag) -> s16x8 {
    return *(const s16x8*)(b + (frag * 64 + lane) * 16);
  };
  auto ldw = [&](int frag) -> s16x8 { return ((const s16x8*)pw)[frag * 64 + lane]; };

  int tt = blockIdx.x;
  if (tt < ntc) { issueA(tt); issueT(tt); }

  for (; tt < ntc; tt += gridDim.x) {
    const int row0 = (t0 + tt) * 64;
    const int tn = tt + gridDim.x;
    const s16x8* fB = (const s16x8*)stage + (size_t)tt * 512;

    // ---- stage: cf regs -> bf16 frag-linear LDS --------------------------
    {
      u32x4 s = { cvtpk(cfr0.x, cfr0.y), cvtpk(cfr0.z, cfr0.w),
                  cvtpk(cfr1.x, cfr1.y), cvtpk(cfr1.z, cfr1.w) };
      int dst16 = ((rcf >> 4) * 2 + (cb >> 2)) * 64 + (cb & 3) * 16 + (rcf & 15);
      *(u32x4*)(cfA + dst16 * 16) = s;
    }
    if (tn < ntc) issueA(tn);       // in flight through b1..b4 + decoder
    bsync();                        // b1

    float xr[4][4];

    // ---- Layer 0: xr = silu(g0*(feat@W0+b0)+be0) + ts; x0 = bf16(xr) -----
    {
      s16x8 bw0 = ldw(w * 2), bw1 = ldw(w * 2 + 1);
      s16x8 bg0 = ldw(16 + w * 2), bg1 = ldw(16 + w * 2 + 1);
      s16x8 bb0 = ldw(32 + w * 2), bb1 = ldw(32 + w * 2 + 1);
      float f0bv = f0b[col], gabv = gab[col], bebv = beb[col];
#pragma unroll
      for (int rg = 0; rg < 4; ++rg) {
        s16x8 a0 = fB[(rg * 2) * 64 + lane], a1 = fB[(rg * 2 + 1) * 64 + lane];
        s16x8 c0 = ldF(cfA, rg * 2), c1 = ldF(cfA, rg * 2 + 1);
        f32x4 t = {0.f, 0.f, 0.f, 0.f};
        t = MFMA16(a0, bw0, t); t = MFMA16(a1, bw1, t);
        f32x4 ga = {0.f, 0.f, 0.f, 0.f};
        ga = MFMA16(c0, bg0, ga); ga = MFMA16(c1, bg1, ga);
        f32x4 be = {0.f, 0.f, 0.f, 0.f};
        be = MFMA16(c0, bb0, be); be = MFMA16(c1, bb1, be);
        char* xbase = x0 + (rg * 4 + cbase) * 1024 + ce;
#pragma unroll
        for (int rr = 0; rr < 4; ++rr) {
          float z = (ga[rr] + gabv) * (t[rr] + f0bv) + (be[rr] + bebv);
          float sl = z * __builtin_amdgcn_rcpf(1.f + __expf(-z));
          xr[rg][rr] = sl + tsr[rg][rr];
          *(short*)(xbase + (cslot + g16 * 4 + rr) * 16) = f2bf1(xr[rg][rr]);
        }
      }
    }
    if (tn < ntc) issueT(tn);       // in flight through b2..b4 + next stage
    bsync();                        // b2

    // ---- Residual FiLM blocks: read src -> write dst -> barrier ----------
#pragma unroll
    for (int i = 0; i < 2; ++i) {
      const char* xsrc = i ? x1 : x0;
      char* xdst = i ? x0 : x1;
      s16x8 bh0 = ldw(112 + i * 32 + w * 4);
      s16x8 bh1 = ldw(112 + i * 32 + w * 4 + 1);
      s16x8 bh2 = ldw(112 + i * 32 + w * 4 + 2);
      s16x8 bh3 = ldw(112 + i * 32 + w * 4 + 3);
      s16x8 bg0 = ldw(16 + (i + 1) * 32 + w * 2);
      s16x8 bg1 = ldw(16 + (i + 1) * 32 + w * 2 + 1);
      s16x8 bb0 = ldw(16 + (i + 1) * 32 + 16 + w * 2);
      s16x8 bb1 = ldw(16 + (i + 1) * 32 + 16 + w * 2 + 1);
      float fhbv = fhb[i * 128 + col];
      float gabv = gab[(i + 1) * 128 + col];
      float bebv = beb[(i + 1) * 128 + col];
#pragma unroll
      for (int rg = 0; rg < 4; ++rg) {
        s16x8 xa = ldF(xsrc, rg * 4), xb = ldF(xsrc, rg * 4 + 1);
        s16x8 xc = ldF(xsrc, rg * 4 + 2), xd = ldF(xsrc, rg * 4 + 3);
        s16x8 c0 = ldF(cfA, rg * 2), c1 = ldF(cfA, rg * 2 + 1);
        f32x4 t = {0.f, 0.f, 0.f, 0.f};
        t = MFMA16(xa, bh0, t); t = MFMA16(xb, bh1, t);
        t = MFMA16(xc, bh2, t); t = MFMA16(xd, bh3, t);
        f32x4 ga = {0.f, 0.f, 0.f, 0.f};
        ga = MFMA16(c0, bg0, ga); ga = MFMA16(c1, bg1, ga);
        f32x4 be = {0.f, 0.f, 0.f, 0.f};
        be = MFMA16(c0, bb0, be); be = MFMA16(c1, bb1, be);
        char* xbase = xdst + (rg * 4 + cbase) * 1024 + ce;
#pragma unroll
        for (int rr = 0; rr < 4; ++rr) {
          float zz = (ga[rr] + gabv) * (t[rr] + fhbv) + (be[rr] + bebv);
          xr[rg][rr] += zz * __builtin_amdgcn_rcpf(1.f + __expf(-zz));
          *(short*)(xbase + (cslot + g16 * 4 + rr) * 16) = f2bf1(xr[rg][rr]);
        }
      }
      bsync();                      // b3 (i=0), b4 (i=1)
    }

    // ---- Decoder (waves 0-3): swapped operands, x as B-frag from x0 ------
    if (w < 4) {
      const int rg = w;
      s16x8 xF0 = ldF(x0, rg * 4), xF1 = ldF(x0, rg * 4 + 1);
      s16x8 xF2 = ldF(x0, rg * 4 + 2), xF3 = ldF(x0, rg * 4 + 3);
      float s = 0.f;
#pragma unroll
      for (int ct = 0; ct < 4; ++ct) {
        f32x4 hh = {0.f, 0.f, 0.f, 0.f};
        hh = MFMA16(ldw(176 + ct * 4 + 0), xF0, hh);
        hh = MFMA16(ldw(176 + ct * 4 + 1), xF1, hh);
        hh = MFMA16(ldw(176 + ct * 4 + 2), xF2, hh);
        hh = MFMA16(ldw(176 + ct * 4 + 3), xF3, hh);
        f32x4 db = *(const f32x4*)&dpk[ct * 256 + lane * 4];
        f32x4 wv = *(const f32x4*)&dpk[1024 + ct * 256 + lane * 4];
#pragma unroll
        for (int rr = 0; rr < 4; ++rr)
          s += fmaxf(hh[rr] + db[rr], 0.f) * wv[rr];
      }
      s += __shfl_xor(s, 16);
      s += __shfl_xor(s, 32);
      if (g16 == 0) {
        int grow = row0 + rg * 16 + l15;
        if (grow < n) out[grow] = s + d2b0;
      }
    }
    // no barrier here: next stage writes cfA (last read before b4); decoder
    // reads x0 (next written only after b1).  Ordering via b4 / b1.
  }
}

extern "C" void kernel_launch(void* const* d_in, const int* in_sizes, int n_in,
                              void* d_out, int out_size, void* d_ws, size_t ws_size,
                              hipStream_t stream) {
  int n = in_sizes[0];
  short* pw = (short*)d_ws;                        // 192 KiB
  float* dpk = (float*)((char*)d_ws + 192 * 1024); // 8 KiB decoder bias pack
  const size_t stage_off = 256 * 1024;
  short* stage = (short*)((char*)d_ws + stage_off);
  int ntiles = (n + 63) / 64;
  long long avail = (long long)ws_size - (long long)stage_off;
  int chunk = (int)(avail > 8192 ? avail / 8192 : 1);
  if (chunk > ntiles) chunk = ntiles;
  if (chunk < 1) chunk = 1;

  pack_w<<<196, 512, 0, stream>>>(
      (const float*)d_in[12],  // film0_fcW
      (const float*)d_in[14],  // filmh_fcW
      (const float*)d_in[16],  // gammaW
      (const float*)d_in[18],  // betaW
      (const float*)d_in[20],  // decW1
      (const float*)d_in[21],  // decb1  (dec pack)
      (const float*)d_in[22],  // decW2  (dec pack)
      pw, dpk);

  for (int t0 = 0; t0 < ntiles; t0 += chunk) {
    int nb = ntiles - t0 < chunk ? ntiles - t0 : chunk;
    ngc_gather<<<nb, 512, 0, stream>>>(
        (const float*)d_in[0],   // coords
        (const float*)d_in[1],   // angles
        (const float*)d_in[2],   // rho
        (const float*)d_in[3],   // rho_n
        (const float*)d_in[6],   // gt0
        (const float*)d_in[7],   // gr0
        (const float*)d_in[8],   // gt1
        (const float*)d_in[9],   // gr1
        (const float*)d_in[10],  // gt2
        (const float*)d_in[11],  // gr2
        stage, n, t0);
    int gb = nb < GEMM_BLK ? nb : GEMM_BLK;
    ngc_gemm<<<gb, 512, 0, stream>>>(
        (const float*)d_in[4],   // curve_feats
        (const float*)d_in[5],   // type_sample
        (const float*)d_in[13],  // film0_fcb
        (const float*)d_in[15],  // filmh_fcb
        (const float*)d_in[17],  // gammab
        (const float*)d_in[19],  // betab
        (const float*)d_in[23],  // decb2
        pw, dpk, stage, (float*)d_out, n, t0, nb);
  }
}